// Round 1
// baseline (622.338 us; speedup 1.0000x reference)
//
#include <hip/hip_runtime.h>
#include <math.h>

// ConvCaps EM routing, fp32 I/O. n=392 positions.
// R21: 768-thread blocks (12 waves), ks in [0,24), KT=12. Theory: kernel is
// latency-bound (VALUBusy 43%, HBM 1%, MfmaUtil 0); parallelism capped at
// 3.06 waves/SIMD by grid geometry (392 blocks x 8 waves). 768 threads per
// position raises resident waves +50% and cuts per-thread k-work 18->12.
// Requires VGPR<=85 (__launch_bounds__(768,6) -> 6 waves/SIMD -> 2 blocks/CU)
// and static LDS < 64KB (sPart shrunk via two-round 12->6 partial merge).
// Carried from prior session (best 75.9us): single fused kernel, 3 v=P@W
// sweeps, packed fp32 (v_pk_fma), W software-pipeline from L2, DPP
// butterflies, shifted exp2 softmax with loop-invariant A/B/G quadratic form.
// Dead ends (measured): LDS register-prefetch (R12, +17%); 2 positions/block
// (R7, +40%); k-interleave (R16/R19 — compiler pins ~84 VGPR and serializes).

#define NTH 768
#define KK 288
#define KSG 24        // k-groups per sweep iteration (768/32)
#define KT 12         // 288 / 24
#define NW 12         // waves per block
#define MW 6          // merged partial slots (two-round reduce)
#define CC 32
#define PS 16
#define EPSF 1e-8f
#define LAMF 1e-3f
#define HL2PI 0.91893853320467274178f   // 0.5*ln(2*pi)
#define LOG2E 1.4426950408889634f

typedef float v2f __attribute__((ext_vector_type(2)));

__device__ __forceinline__ float4 ld4(const float* p){ return *(const float4*)p; }
__device__ __forceinline__ float rcpf(float x){ return __builtin_amdgcn_rcpf(x); }
__device__ __forceinline__ v2f bc2(float s){ return (v2f){s, s}; }
__device__ __forceinline__ v2f fma2(v2f a, v2f b, v2f c){ return __builtin_elementwise_fma(a, b, c); }

// DPP cross-lane reduce steps (VALU pipe ~2-4cyc vs ds_swizzle ~30cyc).
template<int CTRL>
__device__ __forceinline__ float dpp_add(float x){
  const int p = __builtin_amdgcn_update_dpp(0, __builtin_bit_cast(int, x),
                                            CTRL, 0xF, 0xF, true);
  return x + __builtin_bit_cast(float, p);
}
template<int CTRL>
__device__ __forceinline__ float dpp_max(float x){
  const int p = __builtin_amdgcn_update_dpp(0, __builtin_bit_cast(int, x),
                                            CTRL, 0xF, 0xF, true);
  return fmaxf(x, __builtin_bit_cast(float, p));
}
__device__ __forceinline__ float sum32(float s){
  s = dpp_add<0xB1>(s); s = dpp_add<0x4E>(s);
  s = dpp_add<0x141>(s); s = dpp_add<0x140>(s);
  s += __shfl_xor(s, 16);
  return s;
}

extern "C" __global__ void __launch_bounds__(NTH, 6)
convcaps_em_kernel(const float* __restrict__ x, const float* __restrict__ wgt,
                   const float* __restrict__ beta_a, const float* __restrict__ beta_u,
                   float* __restrict__ out)
{
  __shared__ float sP[KK*PS];        // poses, xor-swizzled groups (18432 B)
  __shared__ float sA[KK];           // f = a/(a+eps) (1152 B)
  __shared__ float sPart[MW*CC*33];  // merged wave partials t0|t1[16]|t2[16] (25344 B)
  __shared__ float sMu[CC*17];       // (2176 B)
  __shared__ float sNI2[CC*17];      // -0.5/sigma^2 (2176 B)
  __shared__ float sLs[CC], sLnA[CC], sAo[CC];   // 384 B
  // total ~49.7 KB static; 2 blocks/CU (LDS 99KB/160KB, VGPR 6 waves/SIMD)

  const int tid = threadIdx.x;
  const int n   = blockIdx.x;
  const int b   = n / 49;
  const int r49 = n - b*49;
  const int ohi = r49 / 7;
  const int owi = r49 - ohi*7;

  const float* xw = x + ((size_t)b*16 + (size_t)(ohi*2))*16*544 + (size_t)(owi*2)*544;

  const int c  = tid & 31;    // sweep layout: c in-wave (softmax over c)
  const int ks = tid >> 5;    // k-group 0..23
  const int w  = tid >> 6;    // wave 0..11
  const int cc = tid >> 4;    // stats layout: one thread per (cc, pp), tid<512
  const int pp = tid & 15;

  // ---- stage poses (xor-swizzled groups) ----
  for (int idx = tid; idx < KK*PS/4; idx += NTH) {   // 1152 float4s
    const int sp  = idx >> 7;
    const int ch4 = idx & 127;
    const int kh = sp/3, kw = sp - kh*3;
    const float4 v = ld4(&xw[kh*(16*544) + kw*544 + ch4*4]);
    const int k = sp*32 + (ch4 >> 2);
    const int g = ch4 & 3;
    *(float4*)&sP[(k<<4) + ((g ^ ((k>>1)&3))<<2)] = v;
  }
  // ---- stage activations ----
  if (tid < KK/4) {
    const int sp  = tid >> 3;
    const int bc4 = tid & 7;
    const int kh = sp/3, kw = sp - kh*3;
    const float4 v = ld4(&xw[kh*(16*544) + kw*544 + 512 + bc4*4]);
    *(float4*)&sA[sp*32 + bc4*4] = v;
  }
  __syncthreads();
  if (tid < KK) { const float a = sA[tid]; sA[tid] = a * rcpf(a + EPSF); }
  __syncthreads();

  float t0;
  v2f t1[8], t2[8];    // packed moment accumulators

  // ---- stats phase (two-round 12->6 wave-partial merge, then final reduce) ----
  auto stats = [&](){
    t0 += __shfl_xor(t0, 32);
#pragma unroll
    for (int q = 0; q < 8; ++q) {
      t1[q].x += __shfl_xor(t1[q].x, 32);
      t1[q].y += __shfl_xor(t1[q].y, 32);
      t2[q].x += __shfl_xor(t2[q].x, 32);
      t2[q].y += __shfl_xor(t2[q].y, 32);
    }
    const bool lohalf = (tid & 32) == 0;
    if (lohalf && w >= MW) {          // waves 6..11 store slots 0..5
      float* pr = &sPart[((w - MW)*CC + c)*33];
      pr[0] = t0;
#pragma unroll
      for (int q = 0; q < 8; ++q) {
        pr[1 + 2*q]     = t1[q].x;  pr[1 + 2*q + 1]  = t1[q].y;
        pr[17 + 2*q]    = t2[q].x;  pr[17 + 2*q + 1] = t2[q].y;
      }
    }
    __syncthreads();
    if (lohalf && w < MW) {           // waves 0..5 merge into slot w
      float* pr = &sPart[(w*CC + c)*33];
      pr[0] += t0;
#pragma unroll
      for (int q = 0; q < 8; ++q) {
        pr[1 + 2*q]     += t1[q].x;  pr[1 + 2*q + 1]  += t1[q].y;
        pr[17 + 2*q]    += t2[q].x;  pr[17 + 2*q + 1] += t2[q].y;
      }
    }
    __syncthreads();
    if (tid < 512) {
      float T0 = 0.f, T1 = 0.f, T2 = 0.f;
#pragma unroll
      for (int j = 0; j < MW; ++j) {
        const float* pr = &sPart[(j*CC + cc)*33];
        T0 += pr[0]; T1 += pr[1+pp]; T2 += pr[17+pp];
      }
      const float z   = rcpf(T0 + EPSF);
      const float mu  = T1 * z;
      const float s0  = T0 * z;
      const float var = fmaxf(T2*z - mu*mu*(2.f - s0), 0.f) + EPSF;
      sMu[cc*17 + pp]  = mu;
      sNI2[cc*17 + pp] = -0.5f * rcpf(var);
      float lsum = 0.5f * __logf(var);
      lsum = dpp_add<0xB1>(lsum); lsum = dpp_add<0x4E>(lsum);
      lsum = dpp_add<0x141>(lsum); lsum = dpp_add<0x140>(lsum);
      if (pp == 0) {
        const float cost = (16.f*beta_u[cc] + lsum) * T0;   // r_sum = T0
        const float ao = rcpf(1.f + __expf(-(LAMF*(beta_a[cc] - cost))));
        sAo[cc] = ao; sLnA[cc] = __logf(ao); sLs[cc] = lsum;
      }
    }
    __syncthreads();
  };

  const float4* wg4 = (const float4*)wgt;

  // ---- sweep 0 (it=0): r uniform -> rr = f/32, W software-pipelined ----
  t0 = 0.f;
#pragma unroll
  for (int q = 0; q < 8; ++q) { t1[q] = bc2(0.f); t2[q] = bc2(0.f); }
  float4 cw0, cw1, cw2, cw3;
  {
    const size_t base = ((size_t)(ks*32 + c))*4;   // kt=0 -> k=ks
    cw0 = wg4[base]; cw1 = wg4[base+1]; cw2 = wg4[base+2]; cw3 = wg4[base+3];
  }
  for (int kt = 0; kt < KT; ++kt) {
    const int k = kt*KSG + ks;
    const int kn = ((kt+1 < KT) ? kt+1 : kt)*KSG + ks;
    float4 nw0, nw1, nw2, nw3;
    {
      const size_t base = ((size_t)(kn*32 + c))*4;
      nw0 = wg4[base]; nw1 = wg4[base+1]; nw2 = wg4[base+2]; nw3 = wg4[base+3];
    }
    const v2f w0lo = {cw0.x,cw0.y}, w0hi = {cw0.z,cw0.w};
    const v2f w1lo = {cw1.x,cw1.y}, w1hi = {cw1.z,cw1.w};
    const v2f w2lo = {cw2.x,cw2.y}, w2hi = {cw2.z,cw2.w};
    const v2f w3lo = {cw3.x,cw3.y}, w3hi = {cw3.z,cw3.w};
    const int sw = (k>>1)&3;
    const float* pb = &sP[k<<4];
    const float4 Pi[4] = { ld4(pb + ((0^sw)<<2)), ld4(pb + ((1^sw)<<2)),
                           ld4(pb + ((2^sw)<<2)), ld4(pb + ((3^sw)<<2)) };
    const float rr = sA[k] * (1.0f/32.0f);
    t0 += rr;
    const v2f rr2 = bc2(rr);
#pragma unroll
    for (int i = 0; i < 4; ++i) {
      v2f lo = bc2(Pi[i].x) * w0lo;
      lo = fma2(bc2(Pi[i].y), w1lo, lo);
      lo = fma2(bc2(Pi[i].z), w2lo, lo);
      lo = fma2(bc2(Pi[i].w), w3lo, lo);
      v2f hi = bc2(Pi[i].x) * w0hi;
      hi = fma2(bc2(Pi[i].y), w1hi, hi);
      hi = fma2(bc2(Pi[i].z), w2hi, hi);
      hi = fma2(bc2(Pi[i].w), w3hi, hi);
      const v2f mlo = rr2 * lo, mhi = rr2 * hi;
      t1[i*2]   += mlo;  t2[i*2]   = fma2(mlo, lo, t2[i*2]);
      t1[i*2+1] += mhi;  t2[i*2+1] = fma2(mhi, hi, t2[i*2+1]);
    }
    cw0 = nw0; cw1 = nw1; cw2 = nw2; cw3 = nw3;
  }
  stats();

  // ---- sweeps 1,2: exponent = Sum (A*v+B)*v + G; shifted exp2 softmax ----
  for (int it = 1; it < 3; ++it) {
    // loop-invariant per (sweep, c): A = log2e*ni2, B = -2*log2e*ni2*mu,
    // G = log2e*(Sum ni2*mu^2 + lcv - M)
    v2f A2[8], B2[8];
    float gsum = 0.f;
#pragma unroll
    for (int q = 0; q < 8; ++q) {
      const v2f m2 = (v2f){ sMu[c*17 + 2*q],  sMu[c*17 + 2*q + 1] };
      const v2f n2 = (v2f){ sNI2[c*17 + 2*q], sNI2[c*17 + 2*q + 1] };
      const v2f nm = n2 * m2;
      A2[q] = bc2(LOG2E) * n2;
      B2[q] = bc2(-2.f*LOG2E) * nm;
      const v2f g2 = nm * m2;
      gsum += g2.x + g2.y;
    }
    float lcv = sLnA[c] - sLs[c] - 16.f*HL2PI;
    float M = lcv;
    M = dpp_max<0xB1>(M);  M = dpp_max<0x4E>(M);
    M = dpp_max<0x141>(M); M = dpp_max<0x140>(M);
    M = fmaxf(M, __shfl_xor(M, 16));
    const float G = LOG2E*(gsum + lcv - M);
    t0 = 0.f;
#pragma unroll
    for (int q = 0; q < 8; ++q) { t1[q] = bc2(0.f); t2[q] = bc2(0.f); }
    {
      const size_t base = ((size_t)(ks*32 + c))*4;
      cw0 = wg4[base]; cw1 = wg4[base+1]; cw2 = wg4[base+2]; cw3 = wg4[base+3];
    }
    for (int kt = 0; kt < KT; ++kt) {
      const int k = kt*KSG + ks;
      const int kn = ((kt+1 < KT) ? kt+1 : kt)*KSG + ks;
      float4 nw0, nw1, nw2, nw3;
      {
        const size_t base = ((size_t)(kn*32 + c))*4;
        nw0 = wg4[base]; nw1 = wg4[base+1]; nw2 = wg4[base+2]; nw3 = wg4[base+3];
      }
      const v2f w0lo = {cw0.x,cw0.y}, w0hi = {cw0.z,cw0.w};
      const v2f w1lo = {cw1.x,cw1.y}, w1hi = {cw1.z,cw1.w};
      const v2f w2lo = {cw2.x,cw2.y}, w2hi = {cw2.z,cw2.w};
      const v2f w3lo = {cw3.x,cw3.y}, w3hi = {cw3.z,cw3.w};
      const int sw = (k>>1)&3;
      const float* pb = &sP[k<<4];
      const float4 Pi[4] = { ld4(pb + ((0^sw)<<2)), ld4(pb + ((1^sw)<<2)),
                             ld4(pb + ((2^sw)<<2)), ld4(pb + ((3^sw)<<2)) };
      v2f v[8];
#pragma unroll
      for (int i = 0; i < 4; ++i) {
        v2f lo = bc2(Pi[i].x) * w0lo;
        lo = fma2(bc2(Pi[i].y), w1lo, lo);
        lo = fma2(bc2(Pi[i].z), w2lo, lo);
        lo = fma2(bc2(Pi[i].w), w3lo, lo);
        v2f hi = bc2(Pi[i].x) * w0hi;
        hi = fma2(bc2(Pi[i].y), w1hi, hi);
        hi = fma2(bc2(Pi[i].z), w2hi, hi);
        hi = fma2(bc2(Pi[i].w), w3hi, hi);
        v[i*2] = lo; v[i*2+1] = hi;
      }
      v2f acc2 = bc2(0.f);
#pragma unroll
      for (int q = 0; q < 8; ++q) {
        const v2f h = fma2(A2[q], v[q], B2[q]);
        acc2 = fma2(h, v[q], acc2);
      }
      const float ex = acc2.x + acc2.y + G;      // log2-domain exponent <= ~0
      const float e = exp2f(ex);
      const float s = sum32(e);
      const float rr = e * rcpf(s + 1e-37f) * sA[k];   // r * a/(a+eps)
      t0 += rr;
      const v2f rr2 = bc2(rr);
#pragma unroll
      for (int q = 0; q < 8; ++q) {
        const v2f tmp = rr2 * v[q];
        t1[q] += tmp;
        t2[q] = fma2(tmp, v[q], t2[q]);
      }
      cw0 = nw0; cw1 = nw1; cw2 = nw2; cw3 = nw3;
    }
    stats();
  }

  // ---- epilogue ----
  if (tid < 512) out[(size_t)n*544 + tid] = sMu[(tid>>4)*17 + (tid&15)];
  if (tid < CC)  out[(size_t)n*544 + 512 + tid] = sAo[tid];
}

extern "C" void kernel_launch(void* const* d_in, const int* in_sizes, int n_in,
                              void* d_out, int out_size, void* d_ws, size_t ws_size,
                              hipStream_t stream) {
  (void)in_sizes; (void)n_in; (void)d_ws; (void)ws_size; (void)out_size;
  const float* x  = (const float*)d_in[0];
  const float* w  = (const float*)d_in[1];
  const float* ba = (const float*)d_in[2];
  const float* bu = (const float*)d_in[3];
  float* out = (float*)d_out;
  convcaps_em_kernel<<<dim3(392), dim3(NTH), 0, stream>>>(x, w, ba, bu, out);
}

// Round 2
// 138.188 us; speedup vs baseline: 4.5035x; 4.5035x over previous
//
#include <hip/hip_runtime.h>
#include <math.h>

// ConvCaps EM routing, fp32 I/O. n=392 positions.
// R22: 768-thread blocks (12 waves), ks in [0,24), KT=12 — retry of the TLP
// theory (kernel is latency-bound: VALUBusy 43%, HBM 1%) with ORGANIC low
// VGPR instead of forced launch_bounds. R21 post-mortem: __launch_bounds__
// (768,6) made the backend clamp to 40 VGPR + 1 GB scratch spills (WRITE_SIZE
// 833KB->1GB) -> 594us. NEVER use the min-waves arg here.
// Register diet this round (target <=85 so 2 blocks/CU = 6 waves/SIMD):
//  - no W software pipeline (frees 16 VGPR nw0-3; 6-wave TLP covers L2 lat)
//  - A2/B2/gsum precomputed in stats() into LDS (sABf, stride 18,
//    conflict-free b64), streamed per-kt via opaque-offset asm (anti-LICM)
//    -> frees 32 VGPR
//  - #pragma unroll 1 on kt loops
// Carried: packed fp32 (v_pk_fma), DPP butterflies, shifted exp2 softmax,
// xor-swizzled pose tiles, two-round 12->6 wave-partial merge in stats.
// Dead ends (measured): launch_bounds min-waves (R3/R8/R21: spills);
// LDS register-prefetch (R12 +17%); 2 positions/block (R7 +40%);
// k-interleave (R16/R19: compiler pins ~84 VGPR and serializes).

#define NTH 768
#define KK 288
#define KSG 24        // k-groups per sweep iteration (768/32)
#define KT 12         // 288 / 24
#define MW 6          // merged partial slots (two-round 12->6 reduce)
#define CC 32
#define PS 16
#define EPSF 1e-8f
#define LAMF 1e-3f
#define HL2PI 0.91893853320467274178f   // 0.5*ln(2*pi)
#define LOG2E 1.4426950408889634f

typedef float v2f __attribute__((ext_vector_type(2)));

__device__ __forceinline__ float4 ld4(const float* p){ return *(const float4*)p; }
__device__ __forceinline__ float rcpf(float x){ return __builtin_amdgcn_rcpf(x); }
__device__ __forceinline__ v2f bc2(float s){ return (v2f){s, s}; }
__device__ __forceinline__ v2f fma2(v2f a, v2f b, v2f c){ return __builtin_elementwise_fma(a, b, c); }

template<int CTRL>
__device__ __forceinline__ float dpp_add(float x){
  const int p = __builtin_amdgcn_update_dpp(0, __builtin_bit_cast(int, x),
                                            CTRL, 0xF, 0xF, true);
  return x + __builtin_bit_cast(float, p);
}
template<int CTRL>
__device__ __forceinline__ float dpp_max(float x){
  const int p = __builtin_amdgcn_update_dpp(0, __builtin_bit_cast(int, x),
                                            CTRL, 0xF, 0xF, true);
  return fmaxf(x, __builtin_bit_cast(float, p));
}
__device__ __forceinline__ float sum32(float s){
  s = dpp_add<0xB1>(s); s = dpp_add<0x4E>(s);
  s = dpp_add<0x141>(s); s = dpp_add<0x140>(s);
  s += __shfl_xor(s, 16);
  return s;
}

extern "C" __global__ void __launch_bounds__(NTH)
convcaps_em_kernel(const float* __restrict__ x, const float* __restrict__ wgt,
                   const float* __restrict__ beta_a, const float* __restrict__ beta_u,
                   float* __restrict__ out)
{
  __shared__ float sP[KK*PS];        // poses, xor-swizzled groups (18432 B)
  __shared__ float sA[KK];           // f = a/(a+eps) (1152 B)
  __shared__ float sPart[MW*CC*33];  // merged wave partials t0|t1[16]|t2[16] (25344 B)
  __shared__ float sMu[CC*17];       // (2176 B)
  __shared__ float sABf[2*CC*18];    // A=log2e*ni2 | B=-2*log2e*ni2*mu (4608 B)
  __shared__ float sG[CC];           // sum_p ni2*mu^2 per c (128 B)
  __shared__ float sLs[CC], sLnA[CC], sAo[CC];   // 384 B
  // total ~52.2 KB static -> 2 blocks/CU (LDS 104KB/160KB) IF vgpr <= ~85

  const int tid = threadIdx.x;
  const int n   = blockIdx.x;
  const int b   = n / 49;
  const int r49 = n - b*49;
  const int ohi = r49 / 7;
  const int owi = r49 - ohi*7;

  const float* xw = x + ((size_t)b*16 + (size_t)(ohi*2))*16*544 + (size_t)(owi*2)*544;

  const int c  = tid & 31;    // sweep layout: c in-wave (softmax over c)
  const int ks = tid >> 5;    // k-group 0..23
  const int w  = tid >> 6;    // wave 0..11
  const int cc = tid >> 4;    // stats layout: one thread per (cc, pp), tid<512
  const int pp = tid & 15;

  // ---- stage poses (xor-swizzled groups) ----
  for (int idx = tid; idx < KK*PS/4; idx += NTH) {   // 1152 float4s
    const int sp  = idx >> 7;
    const int ch4 = idx & 127;
    const int kh = sp/3, kw = sp - kh*3;
    const float4 v = ld4(&xw[kh*(16*544) + kw*544 + ch4*4]);
    const int k = sp*32 + (ch4 >> 2);
    const int g = ch4 & 3;
    *(float4*)&sP[(k<<4) + ((g ^ ((k>>1)&3))<<2)] = v;
  }
  // ---- stage activations ----
  if (tid < KK/4) {
    const int sp  = tid >> 3;
    const int bc4 = tid & 7;
    const int kh = sp/3, kw = sp - kh*3;
    const float4 v = ld4(&xw[kh*(16*544) + kw*544 + 512 + bc4*4]);
    *(float4*)&sA[sp*32 + bc4*4] = v;
  }
  __syncthreads();
  if (tid < KK) { const float a = sA[tid]; sA[tid] = a * rcpf(a + EPSF); }
  __syncthreads();

  float t0;
  v2f t1[8], t2[8];    // packed moment accumulators

  // ---- stats: two-round 12->6 merge, reduce, AND precompute A/B/G to LDS ----
  auto stats = [&](){
    t0 += __shfl_xor(t0, 32);
#pragma unroll
    for (int q = 0; q < 8; ++q) {
      t1[q].x += __shfl_xor(t1[q].x, 32);
      t1[q].y += __shfl_xor(t1[q].y, 32);
      t2[q].x += __shfl_xor(t2[q].x, 32);
      t2[q].y += __shfl_xor(t2[q].y, 32);
    }
    const bool lohalf = (tid & 32) == 0;
    if (lohalf && w >= MW) {          // waves 6..11 store slots 0..5
      float* pr = &sPart[((w - MW)*CC + c)*33];
      pr[0] = t0;
#pragma unroll
      for (int q = 0; q < 8; ++q) {
        pr[1 + 2*q]     = t1[q].x;  pr[1 + 2*q + 1]  = t1[q].y;
        pr[17 + 2*q]    = t2[q].x;  pr[17 + 2*q + 1] = t2[q].y;
      }
    }
    __syncthreads();
    if (lohalf && w < MW) {           // waves 0..5 merge into slot w
      float* pr = &sPart[(w*CC + c)*33];
      pr[0] += t0;
#pragma unroll
      for (int q = 0; q < 8; ++q) {
        pr[1 + 2*q]     += t1[q].x;  pr[1 + 2*q + 1]  += t1[q].y;
        pr[17 + 2*q]    += t2[q].x;  pr[17 + 2*q + 1] += t2[q].y;
      }
    }
    __syncthreads();
    if (tid < 512) {
      float T0 = 0.f, T1 = 0.f, T2 = 0.f;
#pragma unroll
      for (int j = 0; j < MW; ++j) {
        const float* pr = &sPart[(j*CC + cc)*33];
        T0 += pr[0]; T1 += pr[1+pp]; T2 += pr[17+pp];
      }
      const float z   = rcpf(T0 + EPSF);
      const float mu  = T1 * z;
      const float s0  = T0 * z;
      const float var = fmaxf(T2*z - mu*mu*(2.f - s0), 0.f) + EPSF;
      sMu[cc*17 + pp]  = mu;
      const float ni2 = -0.5f * rcpf(var);
      sABf[cc*18 + pp]       = LOG2E * ni2;
      sABf[576 + cc*18 + pp] = (-2.f*LOG2E) * (ni2 * mu);
      float lsum = 0.5f * __logf(var);
      float gp   = ni2 * mu * mu;
      lsum = dpp_add<0xB1>(lsum);  gp = dpp_add<0xB1>(gp);
      lsum = dpp_add<0x4E>(lsum);  gp = dpp_add<0x4E>(gp);
      lsum = dpp_add<0x141>(lsum); gp = dpp_add<0x141>(gp);
      lsum = dpp_add<0x140>(lsum); gp = dpp_add<0x140>(gp);
      if (pp == 0) {
        const float cost = (16.f*beta_u[cc] + lsum) * T0;   // r_sum = T0
        const float ao = rcpf(1.f + __expf(-(LAMF*(beta_a[cc] - cost))));
        sAo[cc] = ao; sLnA[cc] = __logf(ao); sLs[cc] = lsum; sG[cc] = gp;
      }
    }
    __syncthreads();
  };

  const float4* wg4 = (const float4*)wgt;

  // ---- sweep 0 (it=0): r uniform -> rr = f/32; W loaded per-iter (no SWP) ----
  t0 = 0.f;
#pragma unroll
  for (int q = 0; q < 8; ++q) { t1[q] = bc2(0.f); t2[q] = bc2(0.f); }
  {
    const float4* wp = wg4 + (size_t)(ks*32 + c)*4;
#pragma unroll 1
    for (int kt = 0; kt < KT; ++kt) {
      const int k = kt*KSG + ks;
      const float4 w0 = wp[0], w1 = wp[1], w2 = wp[2], w3 = wp[3];
      wp += (size_t)KSG*32*4;
      const v2f w0lo = {w0.x,w0.y}, w0hi = {w0.z,w0.w};
      const v2f w1lo = {w1.x,w1.y}, w1hi = {w1.z,w1.w};
      const v2f w2lo = {w2.x,w2.y}, w2hi = {w2.z,w2.w};
      const v2f w3lo = {w3.x,w3.y}, w3hi = {w3.z,w3.w};
      const int sw = (k>>1)&3;
      const float* pb = &sP[k<<4];
      const float4 Pi[4] = { ld4(pb + ((0^sw)<<2)), ld4(pb + ((1^sw)<<2)),
                             ld4(pb + ((2^sw)<<2)), ld4(pb + ((3^sw)<<2)) };
      const float rr = sA[k] * (1.0f/32.0f);
      t0 += rr;
      const v2f rr2 = bc2(rr);
#pragma unroll
      for (int i = 0; i < 4; ++i) {
        v2f lo = bc2(Pi[i].x) * w0lo;
        lo = fma2(bc2(Pi[i].y), w1lo, lo);
        lo = fma2(bc2(Pi[i].z), w2lo, lo);
        lo = fma2(bc2(Pi[i].w), w3lo, lo);
        v2f hi = bc2(Pi[i].x) * w0hi;
        hi = fma2(bc2(Pi[i].y), w1hi, hi);
        hi = fma2(bc2(Pi[i].z), w2hi, hi);
        hi = fma2(bc2(Pi[i].w), w3hi, hi);
        const v2f mlo = rr2 * lo, mhi = rr2 * hi;
        t1[i*2]   += mlo;  t2[i*2]   = fma2(mlo, lo, t2[i*2]);
        t1[i*2+1] += mhi;  t2[i*2+1] = fma2(mhi, hi, t2[i*2+1]);
      }
    }
  }
  stats();

  // ---- sweeps 1,2: exponent = Sum (A*v+B)*v + G; A/B streamed from LDS ----
  for (int it = 1; it < 3; ++it) {
    float lcv = sLnA[c] - sLs[c] - 16.f*HL2PI;
    float M = lcv;
    M = dpp_max<0xB1>(M);  M = dpp_max<0x4E>(M);
    M = dpp_max<0x141>(M); M = dpp_max<0x140>(M);
    M = fmaxf(M, __shfl_xor(M, 16));
    const float G = LOG2E*(sG[c] + lcv - M);
    t0 = 0.f;
#pragma unroll
    for (int q = 0; q < 8; ++q) { t1[q] = bc2(0.f); t2[q] = bc2(0.f); }
    const float4* wp = wg4 + (size_t)(ks*32 + c)*4;
#pragma unroll 1
    for (int kt = 0; kt < KT; ++kt) {
      const int k = kt*KSG + ks;
      const float4 w0 = wp[0], w1 = wp[1], w2 = wp[2], w3 = wp[3];
      wp += (size_t)KSG*32*4;
      const v2f w0lo = {w0.x,w0.y}, w0hi = {w0.z,w0.w};
      const v2f w1lo = {w1.x,w1.y}, w1hi = {w1.z,w1.w};
      const v2f w2lo = {w2.x,w2.y}, w2hi = {w2.z,w2.w};
      const v2f w3lo = {w3.x,w3.y}, w3hi = {w3.z,w3.w};
      const int sw = (k>>1)&3;
      const float* pb = &sP[k<<4];
      const float4 Pi[4] = { ld4(pb + ((0^sw)<<2)), ld4(pb + ((1^sw)<<2)),
                             ld4(pb + ((2^sw)<<2)), ld4(pb + ((3^sw)<<2)) };
      v2f v[8];
#pragma unroll
      for (int i = 0; i < 4; ++i) {
        v2f lo = bc2(Pi[i].x) * w0lo;
        lo = fma2(bc2(Pi[i].y), w1lo, lo);
        lo = fma2(bc2(Pi[i].z), w2lo, lo);
        lo = fma2(bc2(Pi[i].w), w3lo, lo);
        v2f hi = bc2(Pi[i].x) * w0hi;
        hi = fma2(bc2(Pi[i].y), w1hi, hi);
        hi = fma2(bc2(Pi[i].z), w2hi, hi);
        hi = fma2(bc2(Pi[i].w), w3hi, hi);
        v[i*2] = lo; v[i*2+1] = hi;
      }
      // opaque offset: keep A/B loads IN-LOOP (anti-LICM; reg diet)
      int abo = c*18;
      asm volatile("" : "+v"(abo));
      v2f acc2 = bc2(0.f);
#pragma unroll
      for (int q = 0; q < 8; ++q) {
        const v2f A2 = *(const v2f*)&sABf[abo + 2*q];
        const v2f B2 = *(const v2f*)&sABf[576 + abo + 2*q];
        const v2f h = fma2(A2, v[q], B2);
        acc2 = fma2(h, v[q], acc2);
      }
      const float ex = acc2.x + acc2.y + G;      // log2-domain exponent <= ~0
      const float e = exp2f(ex);
      const float s = sum32(e);
      const float rr = e * rcpf(s + 1e-37f) * sA[k];   // r * a/(a+eps)
      t0 += rr;
      const v2f rr2 = bc2(rr);
#pragma unroll
      for (int q = 0; q < 8; ++q) {
        const v2f tmp = rr2 * v[q];
        t1[q] += tmp;
        t2[q] = fma2(tmp, v[q], t2[q]);
      }
    }
    stats();
  }

  // ---- epilogue ----
  if (tid < 512) out[(size_t)n*544 + tid] = sMu[(tid>>4)*17 + (tid&15)];
  if (tid < CC)  out[(size_t)n*544 + 512 + tid] = sAo[tid];
}

extern "C" void kernel_launch(void* const* d_in, const int* in_sizes, int n_in,
                              void* d_out, int out_size, void* d_ws, size_t ws_size,
                              hipStream_t stream) {
  (void)in_sizes; (void)n_in; (void)d_ws; (void)ws_size; (void)out_size;
  const float* x  = (const float*)d_in[0];
  const float* w  = (const float*)d_in[1];
  const float* ba = (const float*)d_in[2];
  const float* bu = (const float*)d_in[3];
  float* out = (float*)d_out;
  convcaps_em_kernel<<<dim3(392), dim3(NTH), 0, stream>>>(x, w, ba, bu, out);
}

// Round 3
// 130.717 us; speedup vs baseline: 4.7610x; 1.0572x over previous
//
#include <hip/hip_runtime.h>
#include <math.h>

// ConvCaps EM routing, fp32 I/O. n=392 positions.
// R23: 768-thread blocks (12 waves), KT=12, retry of TLP theory with the two
// R22 chain regressions removed:
//  (1) W software pipeline RESTORED (R22 dropped it; exposed ~250cy L2
//      latency per kt iter -> VALUBusy 43->35%). Costs +16 VGPR: 64->~80.
//      Hard budget: allocated VGPR <= 80 keeps 6 waves/SIMD (2 blocks/CU).
//  (2) sABf stride 18 -> 17: stride-18 start banks were even-only with
//      c/c+16 colliding -> SQ_LDS_BANK_CONFLICT 345K->7.5M in R22. 17 is
//      coprime with 32 -> bijective bank map, conflict-free b32 reads.
// R21 post-mortem: __launch_bounds__(768,6) clamped to 40 VGPR + 1GB scratch
// (594us). NEVER use the min-waves arg here — organic allocation only.
// Carried: packed fp32 (v_pk_fma), DPP butterflies, shifted exp2 softmax,
// xor-swizzled pose tiles, two-round 12->6 wave-partial merge, A/B/G
// precomputed in stats() to LDS (reg diet), opaque-offset anti-LICM asm.
// Dead ends (measured): launch_bounds min-waves (R3/R8/R21: spills);
// LDS register-prefetch (R12 +17%); 2 positions/block (R7 +40%);
// k-interleave (R16/R19); no-SWP + stride-18 A/B (R22: 93us).

#define NTH 768
#define KK 288
#define KSG 24        // k-groups per sweep iteration (768/32)
#define KT 12         // 288 / 24
#define MW 6          // merged partial slots (two-round 12->6 reduce)
#define CC 32
#define PS 16
#define EPSF 1e-8f
#define LAMF 1e-3f
#define HL2PI 0.91893853320467274178f   // 0.5*ln(2*pi)
#define LOG2E 1.4426950408889634f

typedef float v2f __attribute__((ext_vector_type(2)));

__device__ __forceinline__ float4 ld4(const float* p){ return *(const float4*)p; }
__device__ __forceinline__ float rcpf(float x){ return __builtin_amdgcn_rcpf(x); }
__device__ __forceinline__ v2f bc2(float s){ return (v2f){s, s}; }
__device__ __forceinline__ v2f fma2(v2f a, v2f b, v2f c){ return __builtin_elementwise_fma(a, b, c); }

template<int CTRL>
__device__ __forceinline__ float dpp_add(float x){
  const int p = __builtin_amdgcn_update_dpp(0, __builtin_bit_cast(int, x),
                                            CTRL, 0xF, 0xF, true);
  return x + __builtin_bit_cast(float, p);
}
template<int CTRL>
__device__ __forceinline__ float dpp_max(float x){
  const int p = __builtin_amdgcn_update_dpp(0, __builtin_bit_cast(int, x),
                                            CTRL, 0xF, 0xF, true);
  return fmaxf(x, __builtin_bit_cast(float, p));
}
__device__ __forceinline__ float sum32(float s){
  s = dpp_add<0xB1>(s); s = dpp_add<0x4E>(s);
  s = dpp_add<0x141>(s); s = dpp_add<0x140>(s);
  s += __shfl_xor(s, 16);
  return s;
}

extern "C" __global__ void __launch_bounds__(NTH)
convcaps_em_kernel(const float* __restrict__ x, const float* __restrict__ wgt,
                   const float* __restrict__ beta_a, const float* __restrict__ beta_u,
                   float* __restrict__ out)
{
  __shared__ float sP[KK*PS];        // poses, xor-swizzled groups (18432 B)
  __shared__ float sA[KK];           // f = a/(a+eps) (1152 B)
  __shared__ float sPart[MW*CC*33];  // merged wave partials t0|t1[16]|t2[16] (25344 B)
  __shared__ float sMu[CC*17];       // (2176 B)
  __shared__ float sABf[2*CC*17];    // A=log2e*ni2 | B=-2*log2e*ni2*mu, stride 17 (4352 B)
  __shared__ float sG[CC];           // sum_p ni2*mu^2 per c (128 B)
  __shared__ float sLs[CC], sLnA[CC], sAo[CC];   // 384 B
  // total ~51.9 KB static -> 2 blocks/CU (LDS 104KB/160KB) IF vgpr <= 80

  const int tid = threadIdx.x;
  const int n   = blockIdx.x;
  const int b   = n / 49;
  const int r49 = n - b*49;
  const int ohi = r49 / 7;
  const int owi = r49 - ohi*7;

  const float* xw = x + ((size_t)b*16 + (size_t)(ohi*2))*16*544 + (size_t)(owi*2)*544;

  const int c  = tid & 31;    // sweep layout: c in-wave (softmax over c)
  const int ks = tid >> 5;    // k-group 0..23
  const int w  = tid >> 6;    // wave 0..11
  const int cc = tid >> 4;    // stats layout: one thread per (cc, pp), tid<512
  const int pp = tid & 15;

  // ---- stage poses (xor-swizzled groups) ----
  for (int idx = tid; idx < KK*PS/4; idx += NTH) {   // 1152 float4s
    const int sp  = idx >> 7;
    const int ch4 = idx & 127;
    const int kh = sp/3, kw = sp - kh*3;
    const float4 v = ld4(&xw[kh*(16*544) + kw*544 + ch4*4]);
    const int k = sp*32 + (ch4 >> 2);
    const int g = ch4 & 3;
    *(float4*)&sP[(k<<4) + ((g ^ ((k>>1)&3))<<2)] = v;
  }
  // ---- stage activations ----
  if (tid < KK/4) {
    const int sp  = tid >> 3;
    const int bc4 = tid & 7;
    const int kh = sp/3, kw = sp - kh*3;
    const float4 v = ld4(&xw[kh*(16*544) + kw*544 + 512 + bc4*4]);
    *(float4*)&sA[sp*32 + bc4*4] = v;
  }
  __syncthreads();
  if (tid < KK) { const float a = sA[tid]; sA[tid] = a * rcpf(a + EPSF); }
  __syncthreads();

  float t0;
  v2f t1[8], t2[8];    // packed moment accumulators

  // ---- stats: two-round 12->6 merge, reduce, AND precompute A/B/G to LDS ----
  auto stats = [&](){
    t0 += __shfl_xor(t0, 32);
#pragma unroll
    for (int q = 0; q < 8; ++q) {
      t1[q].x += __shfl_xor(t1[q].x, 32);
      t1[q].y += __shfl_xor(t1[q].y, 32);
      t2[q].x += __shfl_xor(t2[q].x, 32);
      t2[q].y += __shfl_xor(t2[q].y, 32);
    }
    const bool lohalf = (tid & 32) == 0;
    if (lohalf && w >= MW) {          // waves 6..11 store slots 0..5
      float* pr = &sPart[((w - MW)*CC + c)*33];
      pr[0] = t0;
#pragma unroll
      for (int q = 0; q < 8; ++q) {
        pr[1 + 2*q]     = t1[q].x;  pr[1 + 2*q + 1]  = t1[q].y;
        pr[17 + 2*q]    = t2[q].x;  pr[17 + 2*q + 1] = t2[q].y;
      }
    }
    __syncthreads();
    if (lohalf && w < MW) {           // waves 0..5 merge into slot w
      float* pr = &sPart[(w*CC + c)*33];
      pr[0] += t0;
#pragma unroll
      for (int q = 0; q < 8; ++q) {
        pr[1 + 2*q]     += t1[q].x;  pr[1 + 2*q + 1]  += t1[q].y;
        pr[17 + 2*q]    += t2[q].x;  pr[17 + 2*q + 1] += t2[q].y;
      }
    }
    __syncthreads();
    if (tid < 512) {
      float T0 = 0.f, T1 = 0.f, T2 = 0.f;
#pragma unroll
      for (int j = 0; j < MW; ++j) {
        const float* pr = &sPart[(j*CC + cc)*33];
        T0 += pr[0]; T1 += pr[1+pp]; T2 += pr[17+pp];
      }
      const float z   = rcpf(T0 + EPSF);
      const float mu  = T1 * z;
      const float s0  = T0 * z;
      const float var = fmaxf(T2*z - mu*mu*(2.f - s0), 0.f) + EPSF;
      sMu[cc*17 + pp]  = mu;
      const float ni2 = -0.5f * rcpf(var);
      sABf[cc*17 + pp]       = LOG2E * ni2;
      sABf[544 + cc*17 + pp] = (-2.f*LOG2E) * (ni2 * mu);
      float lsum = 0.5f * __logf(var);
      float gp   = ni2 * mu * mu;
      lsum = dpp_add<0xB1>(lsum);  gp = dpp_add<0xB1>(gp);
      lsum = dpp_add<0x4E>(lsum);  gp = dpp_add<0x4E>(gp);
      lsum = dpp_add<0x141>(lsum); gp = dpp_add<0x141>(gp);
      lsum = dpp_add<0x140>(lsum); gp = dpp_add<0x140>(gp);
      if (pp == 0) {
        const float cost = (16.f*beta_u[cc] + lsum) * T0;   // r_sum = T0
        const float ao = rcpf(1.f + __expf(-(LAMF*(beta_a[cc] - cost))));
        sAo[cc] = ao; sLnA[cc] = __logf(ao); sLs[cc] = lsum; sG[cc] = gp;
      }
    }
    __syncthreads();
  };

  const float4* wg4 = (const float4*)wgt;

  // ---- sweep 0 (it=0): r uniform -> rr = f/32; W software-pipelined ----
  t0 = 0.f;
#pragma unroll
  for (int q = 0; q < 8; ++q) { t1[q] = bc2(0.f); t2[q] = bc2(0.f); }
  {
    float4 cw0, cw1, cw2, cw3;
    {
      const size_t base = ((size_t)(ks*32 + c))*4;   // kt=0 -> k=ks
      cw0 = wg4[base]; cw1 = wg4[base+1]; cw2 = wg4[base+2]; cw3 = wg4[base+3];
    }
#pragma unroll 1
    for (int kt = 0; kt < KT; ++kt) {
      const int k = kt*KSG + ks;
      const int kn = ((kt+1 < KT) ? kt+1 : kt)*KSG + ks;
      float4 nw0, nw1, nw2, nw3;
      {
        const size_t base = ((size_t)(kn*32 + c))*4;
        nw0 = wg4[base]; nw1 = wg4[base+1]; nw2 = wg4[base+2]; nw3 = wg4[base+3];
      }
      const v2f w0lo = {cw0.x,cw0.y}, w0hi = {cw0.z,cw0.w};
      const v2f w1lo = {cw1.x,cw1.y}, w1hi = {cw1.z,cw1.w};
      const v2f w2lo = {cw2.x,cw2.y}, w2hi = {cw2.z,cw2.w};
      const v2f w3lo = {cw3.x,cw3.y}, w3hi = {cw3.z,cw3.w};
      const int sw = (k>>1)&3;
      const float* pb = &sP[k<<4];
      const float4 Pi[4] = { ld4(pb + ((0^sw)<<2)), ld4(pb + ((1^sw)<<2)),
                             ld4(pb + ((2^sw)<<2)), ld4(pb + ((3^sw)<<2)) };
      const float rr = sA[k] * (1.0f/32.0f);
      t0 += rr;
      const v2f rr2 = bc2(rr);
#pragma unroll
      for (int i = 0; i < 4; ++i) {
        v2f lo = bc2(Pi[i].x) * w0lo;
        lo = fma2(bc2(Pi[i].y), w1lo, lo);
        lo = fma2(bc2(Pi[i].z), w2lo, lo);
        lo = fma2(bc2(Pi[i].w), w3lo, lo);
        v2f hi = bc2(Pi[i].x) * w0hi;
        hi = fma2(bc2(Pi[i].y), w1hi, hi);
        hi = fma2(bc2(Pi[i].z), w2hi, hi);
        hi = fma2(bc2(Pi[i].w), w3hi, hi);
        const v2f mlo = rr2 * lo, mhi = rr2 * hi;
        t1[i*2]   += mlo;  t2[i*2]   = fma2(mlo, lo, t2[i*2]);
        t1[i*2+1] += mhi;  t2[i*2+1] = fma2(mhi, hi, t2[i*2+1]);
      }
      cw0 = nw0; cw1 = nw1; cw2 = nw2; cw3 = nw3;
    }
  }
  stats();

  // ---- sweeps 1,2: exponent = Sum (A*v+B)*v + G; A/B streamed from LDS ----
  for (int it = 1; it < 3; ++it) {
    float lcv = sLnA[c] - sLs[c] - 16.f*HL2PI;
    float M = lcv;
    M = dpp_max<0xB1>(M);  M = dpp_max<0x4E>(M);
    M = dpp_max<0x141>(M); M = dpp_max<0x140>(M);
    M = fmaxf(M, __shfl_xor(M, 16));
    const float G = LOG2E*(sG[c] + lcv - M);
    t0 = 0.f;
#pragma unroll
    for (int q = 0; q < 8; ++q) { t1[q] = bc2(0.f); t2[q] = bc2(0.f); }
    float4 cw0, cw1, cw2, cw3;
    {
      const size_t base = ((size_t)(ks*32 + c))*4;
      cw0 = wg4[base]; cw1 = wg4[base+1]; cw2 = wg4[base+2]; cw3 = wg4[base+3];
    }
#pragma unroll 1
    for (int kt = 0; kt < KT; ++kt) {
      const int k = kt*KSG + ks;
      const int kn = ((kt+1 < KT) ? kt+1 : kt)*KSG + ks;
      float4 nw0, nw1, nw2, nw3;
      {
        const size_t base = ((size_t)(kn*32 + c))*4;
        nw0 = wg4[base]; nw1 = wg4[base+1]; nw2 = wg4[base+2]; nw3 = wg4[base+3];
      }
      const v2f w0lo = {cw0.x,cw0.y}, w0hi = {cw0.z,cw0.w};
      const v2f w1lo = {cw1.x,cw1.y}, w1hi = {cw1.z,cw1.w};
      const v2f w2lo = {cw2.x,cw2.y}, w2hi = {cw2.z,cw2.w};
      const v2f w3lo = {cw3.x,cw3.y}, w3hi = {cw3.z,cw3.w};
      const int sw = (k>>1)&3;
      const float* pb = &sP[k<<4];
      const float4 Pi[4] = { ld4(pb + ((0^sw)<<2)), ld4(pb + ((1^sw)<<2)),
                             ld4(pb + ((2^sw)<<2)), ld4(pb + ((3^sw)<<2)) };
      v2f v[8];
#pragma unroll
      for (int i = 0; i < 4; ++i) {
        v2f lo = bc2(Pi[i].x) * w0lo;
        lo = fma2(bc2(Pi[i].y), w1lo, lo);
        lo = fma2(bc2(Pi[i].z), w2lo, lo);
        lo = fma2(bc2(Pi[i].w), w3lo, lo);
        v2f hi = bc2(Pi[i].x) * w0hi;
        hi = fma2(bc2(Pi[i].y), w1hi, hi);
        hi = fma2(bc2(Pi[i].z), w2hi, hi);
        hi = fma2(bc2(Pi[i].w), w3hi, hi);
        v[i*2] = lo; v[i*2+1] = hi;
      }
      // opaque offset: keep A/B loads IN-LOOP (anti-LICM; reg diet).
      // stride 17 floats: bank = (17c + p) mod 32, bijective in c -> no conflicts
      int abo = c*17;
      asm volatile("" : "+v"(abo));
      v2f acc2 = bc2(0.f);
#pragma unroll
      for (int q = 0; q < 8; ++q) {
        const v2f A2 = { sABf[abo + 2*q],       sABf[abo + 2*q + 1] };
        const v2f B2 = { sABf[544 + abo + 2*q], sABf[544 + abo + 2*q + 1] };
        const v2f h = fma2(A2, v[q], B2);
        acc2 = fma2(h, v[q], acc2);
      }
      const float ex = acc2.x + acc2.y + G;      // log2-domain exponent <= ~0
      const float e = exp2f(ex);
      const float s = sum32(e);
      const float rr = e * rcpf(s + 1e-37f) * sA[k];   // r * a/(a+eps)
      t0 += rr;
      const v2f rr2 = bc2(rr);
#pragma unroll
      for (int q = 0; q < 8; ++q) {
        const v2f tmp = rr2 * v[q];
        t1[q] += tmp;
        t2[q] = fma2(tmp, v[q], t2[q]);
      }
      cw0 = nw0; cw1 = nw1; cw2 = nw2; cw3 = nw3;
    }
    stats();
  }

  // ---- epilogue ----
  if (tid < 512) out[(size_t)n*544 + tid] = sMu[(tid>>4)*17 + (tid&15)];
  if (tid < CC)  out[(size_t)n*544 + 512 + tid] = sAo[tid];
}

extern "C" void kernel_launch(void* const* d_in, const int* in_sizes, int n_in,
                              void* d_out, int out_size, void* d_ws, size_t ws_size,
                              hipStream_t stream) {
  (void)in_sizes; (void)n_in; (void)d_ws; (void)ws_size; (void)out_size;
  const float* x  = (const float*)d_in[0];
  const float* w  = (const float*)d_in[1];
  const float* ba = (const float*)d_in[2];
  const float* bu = (const float*)d_in[3];
  float* out = (float*)d_out;
  convcaps_em_kernel<<<dim3(392), dim3(NTH), 0, stream>>>(x, w, ba, bu, out);
}

// Round 6
// 119.817 us; speedup vs baseline: 5.1941x; 1.0910x over previous
//
#include <hip/hip_runtime.h>
#include <math.h>

// ConvCaps EM routing, fp32 I/O. n=392 positions, one 512-thread block each.
// R26: 2-stage rotation ONLY (un-bundled from R25's failure). R25 post-mortem:
// absmax 2.3 traced to permlane16_swap with IDENTICAL operands — the HW
// instruction is an in-place two-register row swap; same-register operands
// degenerate to an intra-register swap, both results alias [r1,r0,r3,r2],
// sum = 2*x[i^16]. REVERTED to proven __shfl_xor(s,16) tail. (If rotation
// wins, permlane may be retried with forced-distinct operands via asm.)
// Theory under test (from R0/R24): 76us baseline is latency-bound INSIDE the
// per-iter chain (crit-CU VALU only ~57% busy; Pi ds_read ~120cy + W L2
// ~200cy exposed between issue and use). Fix: per iter, issue W(k)+sA(kp)+
// Pi(k) loads FIRST, run softmax+moments on PREVIOUS v (≈400cy pure-VALU
// chain covers both latencies), then compute v(k). W double-buffer dropped
// (-16 VGPR, softmax now covers W latency); +16 VGPR for pipelined vA.
// HARD CONSTRAINT: VGPR must stay <=128 (2 blocks/CU on crit CUs). No
// __launch_bounds__ min-waves ever (R21: clamp to 40 VGPR + 1GB spills).
// Dead ends (measured): 768-thread blocks (R21/R22/R23); launch_bounds
// min-waves (R3/R8/R21); LDS register-prefetch w/o consumer move (R12 +17%);
// 2 positions/block (R7 +40%); k-interleave (R16/R19); A/B in LDS (R22/R23);
// permlane16_swap with aliased operands (R25: absmax 2.3).

#define NTH 512
#define KK 288
#define KSG 16       // k-groups (512/32)
#define KT 18        // 288 / 16
#define CC 32
#define PS 16
#define EPSF 1e-8f
#define LAMF 1e-3f
#define HL2PI 0.91893853320467274178f   // 0.5*ln(2*pi)
#define LOG2E 1.4426950408889634f

typedef float v2f __attribute__((ext_vector_type(2)));

__device__ __forceinline__ float4 ld4(const float* p){ return *(const float4*)p; }
__device__ __forceinline__ float rcpf(float x){ return __builtin_amdgcn_rcpf(x); }
__device__ __forceinline__ v2f bc2(float s){ return (v2f){s, s}; }
__device__ __forceinline__ v2f fma2(v2f a, v2f b, v2f c){ return __builtin_elementwise_fma(a, b, c); }

// DPP cross-lane reduce steps (VALU pipe ~2-4cyc vs ds_swizzle ~30cyc).
template<int CTRL>
__device__ __forceinline__ float dpp_add(float x){
  const int p = __builtin_amdgcn_update_dpp(0, __builtin_bit_cast(int, x),
                                            CTRL, 0xF, 0xF, true);
  return x + __builtin_bit_cast(float, p);
}
template<int CTRL>
__device__ __forceinline__ float dpp_max(float x){
  const int p = __builtin_amdgcn_update_dpp(0, __builtin_bit_cast(int, x),
                                            CTRL, 0xF, 0xF, true);
  return fmaxf(x, __builtin_bit_cast(float, p));
}
__device__ __forceinline__ float sum32(float s){
  s = dpp_add<0xB1>(s); s = dpp_add<0x4E>(s);
  s = dpp_add<0x141>(s); s = dpp_add<0x140>(s);
  s += __shfl_xor(s, 16);
  return s;
}

extern "C" __global__ void __launch_bounds__(NTH)
convcaps_em_kernel(const float* __restrict__ x, const float* __restrict__ wgt,
                   const float* __restrict__ beta_a, const float* __restrict__ beta_u,
                   float* __restrict__ out)
{
  __shared__ float sP[KK*PS];        // poses, xor-swizzled groups (18432 B)
  __shared__ float sA[KK];           // f = a/(a+eps) (1152 B)
  __shared__ float sPart[8*CC*33];   // wave partials t0|t1[16]|t2[16] (33792 B)
  __shared__ float sMu[CC*17];       // (2176 B)
  __shared__ float sNI2[CC*17];      // -0.5/sigma^2 (2176 B)
  __shared__ float sLs[CC], sLnA[CC], sAo[CC];   // 384 B
  // total ~58.1 KB -> 2 blocks/CU

  const int tid = threadIdx.x;
  const int n   = blockIdx.x;
  const int b   = n / 49;
  const int r49 = n - b*49;
  const int ohi = r49 / 7;
  const int owi = r49 - ohi*7;

  const float* xw = x + ((size_t)b*16 + (size_t)(ohi*2))*16*544 + (size_t)(owi*2)*544;

  const int c  = tid & 31;    // sweep layout: c in-wave (softmax over c)
  const int ks = tid >> 5;    // k-group 0..15
  const int w  = tid >> 6;    // wave 0..7
  const int cc = tid >> 4;    // stats layout: one thread per (cc, pp)
  const int pp = tid & 15;

  // ---- stage poses (xor-swizzled groups) ----
  for (int idx = tid; idx < KK*PS/4; idx += NTH) {   // 1152 float4s
    const int sp  = idx >> 7;
    const int ch4 = idx & 127;
    const int kh = sp/3, kw = sp - kh*3;
    const float4 v = ld4(&xw[kh*(16*544) + kw*544 + ch4*4]);
    const int k = sp*32 + (ch4 >> 2);
    const int g = ch4 & 3;
    *(float4*)&sP[(k<<4) + ((g ^ ((k>>1)&3))<<2)] = v;
  }
  // ---- stage activations ----
  if (tid < KK/4) {
    const int sp  = tid >> 3;
    const int bc4 = tid & 7;
    const int kh = sp/3, kw = sp - kh*3;
    const float4 v = ld4(&xw[kh*(16*544) + kw*544 + 512 + bc4*4]);
    *(float4*)&sA[sp*32 + bc4*4] = v;
  }
  __syncthreads();
  if (tid < KK) { const float a = sA[tid]; sA[tid] = a * rcpf(a + EPSF); }
  __syncthreads();

  float t0;
  v2f t1[8], t2[8];    // packed moment accumulators

  // ---- stats phase (R6-proven layout; unpack pairs at store) ----
  auto stats = [&](){
    t0 += __shfl_xor(t0, 32);
#pragma unroll
    for (int q = 0; q < 8; ++q) {
      t1[q].x += __shfl_xor(t1[q].x, 32);
      t1[q].y += __shfl_xor(t1[q].y, 32);
      t2[q].x += __shfl_xor(t2[q].x, 32);
      t2[q].y += __shfl_xor(t2[q].y, 32);
    }
    if ((tid & 32) == 0) {
      float* pr = &sPart[(w*CC + c)*33];
      pr[0] = t0;
#pragma unroll
      for (int q = 0; q < 8; ++q) {
        pr[1 + 2*q]     = t1[q].x;  pr[1 + 2*q + 1]  = t1[q].y;
        pr[17 + 2*q]    = t2[q].x;  pr[17 + 2*q + 1] = t2[q].y;
      }
    }
    __syncthreads();
    {
      float T0 = 0.f, T1 = 0.f, T2 = 0.f;
#pragma unroll
      for (int j = 0; j < 8; ++j) {
        const float* pr = &sPart[(j*CC + cc)*33];
        T0 += pr[0]; T1 += pr[1+pp]; T2 += pr[17+pp];
      }
      const float z   = rcpf(T0 + EPSF);
      const float mu  = T1 * z;
      const float s0  = T0 * z;
      const float var = fmaxf(T2*z - mu*mu*(2.f - s0), 0.f) + EPSF;
      sMu[cc*17 + pp]  = mu;
      sNI2[cc*17 + pp] = -0.5f * rcpf(var);
      float lsum = 0.5f * __logf(var);
      lsum = dpp_add<0xB1>(lsum); lsum = dpp_add<0x4E>(lsum);
      lsum = dpp_add<0x141>(lsum); lsum = dpp_add<0x140>(lsum);
      if (pp == 0) {
        const float cost = (16.f*beta_u[cc] + lsum) * T0;   // r_sum = T0
        const float ao = rcpf(1.f + __expf(-(LAMF*(beta_a[cc] - cost))));
        sAo[cc] = ao; sLnA[cc] = __logf(ao); sLs[cc] = lsum;
      }
    }
    __syncthreads();
  };

  const float4* wg4 = (const float4*)wgt;

  // v = P@W for one k into 8 packed v2f (16 fp32)
  auto compute_v = [&](v2f (&v)[8], const float4 (&P)[4],
                       const float4& W0, const float4& W1,
                       const float4& W2, const float4& W3){
    const v2f w0lo = {W0.x,W0.y}, w0hi = {W0.z,W0.w};
    const v2f w1lo = {W1.x,W1.y}, w1hi = {W1.z,W1.w};
    const v2f w2lo = {W2.x,W2.y}, w2hi = {W2.z,W2.w};
    const v2f w3lo = {W3.x,W3.y}, w3hi = {W3.z,W3.w};
#pragma unroll
    for (int i = 0; i < 4; ++i) {
      v2f lo = bc2(P[i].x) * w0lo;
      lo = fma2(bc2(P[i].y), w1lo, lo);
      lo = fma2(bc2(P[i].z), w2lo, lo);
      lo = fma2(bc2(P[i].w), w3lo, lo);
      v2f hi = bc2(P[i].x) * w0hi;
      hi = fma2(bc2(P[i].y), w1hi, hi);
      hi = fma2(bc2(P[i].z), w2hi, hi);
      hi = fma2(bc2(P[i].w), w3hi, hi);
      v[i*2] = lo; v[i*2+1] = hi;
    }
  };

  // ---- sweep 0 (it=0): r uniform -> rr = f/32, W software-pipelined ----
  t0 = 0.f;
#pragma unroll
  for (int q = 0; q < 8; ++q) { t1[q] = bc2(0.f); t2[q] = bc2(0.f); }
  {
    float4 cw0, cw1, cw2, cw3;
    {
      const size_t base = ((size_t)(ks*32 + c))*4;   // kt=0 -> k=ks
      cw0 = wg4[base]; cw1 = wg4[base+1]; cw2 = wg4[base+2]; cw3 = wg4[base+3];
    }
#pragma unroll 1
    for (int kt = 0; kt < KT; ++kt) {
      const int k = kt*KSG + ks;
      const int kn = ((kt+1 < KT) ? kt+1 : kt)*KSG + ks;
      float4 nw0, nw1, nw2, nw3;
      {
        const size_t base = ((size_t)(kn*32 + c))*4;
        nw0 = wg4[base]; nw1 = wg4[base+1]; nw2 = wg4[base+2]; nw3 = wg4[base+3];
      }
      const v2f w0lo = {cw0.x,cw0.y}, w0hi = {cw0.z,cw0.w};
      const v2f w1lo = {cw1.x,cw1.y}, w1hi = {cw1.z,cw1.w};
      const v2f w2lo = {cw2.x,cw2.y}, w2hi = {cw2.z,cw2.w};
      const v2f w3lo = {cw3.x,cw3.y}, w3hi = {cw3.z,cw3.w};
      const int sw = (k>>1)&3;
      const float* pb = &sP[k<<4];
      const float4 Pi[4] = { ld4(pb + ((0^sw)<<2)), ld4(pb + ((1^sw)<<2)),
                             ld4(pb + ((2^sw)<<2)), ld4(pb + ((3^sw)<<2)) };
      const float rr = sA[k] * (1.0f/32.0f);
      t0 += rr;
      const v2f rr2 = bc2(rr);
#pragma unroll
      for (int i = 0; i < 4; ++i) {
        v2f lo = bc2(Pi[i].x) * w0lo;
        lo = fma2(bc2(Pi[i].y), w1lo, lo);
        lo = fma2(bc2(Pi[i].z), w2lo, lo);
        lo = fma2(bc2(Pi[i].w), w3lo, lo);
        v2f hi = bc2(Pi[i].x) * w0hi;
        hi = fma2(bc2(Pi[i].y), w1hi, hi);
        hi = fma2(bc2(Pi[i].z), w2hi, hi);
        hi = fma2(bc2(Pi[i].w), w3hi, hi);
        const v2f mlo = rr2 * lo, mhi = rr2 * hi;
        t1[i*2]   += mlo;  t2[i*2]   = fma2(mlo, lo, t2[i*2]);
        t1[i*2+1] += mhi;  t2[i*2+1] = fma2(mhi, hi, t2[i*2+1]);
      }
      cw0 = nw0; cw1 = nw1; cw2 = nw2; cw3 = nw3;
    }
  }
  stats();

  // ---- sweeps 1,2: 2-stage rotation. Per iter: issue W(k)+sA(kp)+Pi(k),
  //      softmax+moments on PREVIOUS v (hides both latencies), compute v(k).
  for (int it = 1; it < 3; ++it) {
    // loop-invariant per (sweep, c): A = log2e*ni2, B = -2*log2e*ni2*mu,
    // G = log2e*(Sum ni2*mu^2 + lcv - M)
    v2f A2[8], B2[8];
    float gsum = 0.f;
#pragma unroll
    for (int q = 0; q < 8; ++q) {
      const v2f m2 = (v2f){ sMu[c*17 + 2*q],  sMu[c*17 + 2*q + 1] };
      const v2f n2 = (v2f){ sNI2[c*17 + 2*q], sNI2[c*17 + 2*q + 1] };
      const v2f nm = n2 * m2;
      A2[q] = bc2(LOG2E) * n2;
      B2[q] = bc2(-2.f*LOG2E) * nm;
      const v2f g2 = nm * m2;
      gsum += g2.x + g2.y;
    }
    float lcv = sLnA[c] - sLs[c] - 16.f*HL2PI;
    float M = lcv;
    M = dpp_max<0xB1>(M);  M = dpp_max<0x4E>(M);
    M = dpp_max<0x141>(M); M = dpp_max<0x140>(M);
    M = fmaxf(M, __shfl_xor(M, 16));
    const float G = LOG2E*(gsum + lcv - M);

    auto softmax_moments = [&](const v2f (&v)[8], float fA){
      v2f acc2 = bc2(0.f);
#pragma unroll
      for (int q = 0; q < 8; ++q) {
        const v2f h = fma2(A2[q], v[q], B2[q]);
        acc2 = fma2(h, v[q], acc2);
      }
      const float ex = acc2.x + acc2.y + G;      // log2-domain exponent <= ~0
      const float e = exp2f(ex);
      const float s = sum32(e);
      const float rr = e * rcpf(s + 1e-37f) * fA;   // r * a/(a+eps)
      t0 += rr;
      const v2f rr2 = bc2(rr);
#pragma unroll
      for (int q = 0; q < 8; ++q) {
        const v2f tmp = rr2 * v[q];
        t1[q] += tmp;
        t2[q] = fma2(tmp, v[q], t2[q]);
      }
    };

    t0 = 0.f;
#pragma unroll
    for (int q = 0; q < 8; ++q) { t1[q] = bc2(0.f); t2[q] = bc2(0.f); }

    v2f vA[8];
    // prologue (kt=0): load W(k0)+Pi(k0), compute vA. Latency exposed once.
    {
      const int k = ks;
      const size_t base = ((size_t)(k*32 + c))*4;
      const float4 w0 = wg4[base], w1 = wg4[base+1], w2 = wg4[base+2], w3 = wg4[base+3];
      const int sw = (k>>1)&3;
      const float* pb = &sP[k<<4];
      const float4 Pi[4] = { ld4(pb + ((0^sw)<<2)), ld4(pb + ((1^sw)<<2)),
                             ld4(pb + ((2^sw)<<2)), ld4(pb + ((3^sw)<<2)) };
      compute_v(vA, Pi, w0, w1, w2, w3);
    }
#pragma unroll 1
    for (int kt = 1; kt < KT; ++kt) {
      const int k  = kt*KSG + ks;
      const int kp = k - KSG;
      // (1) issue W(k) from L2 — consumed after softmax (~400cy later)
      const size_t base = ((size_t)(k*32 + c))*4;
      const float4 w0 = wg4[base], w1 = wg4[base+1], w2 = wg4[base+2], w3 = wg4[base+3];
      // (2) issue sA(kp) BEFORE Pi so its wait is lgkmcnt(4), not a drain
      const float fA = sA[kp];
      // (3) issue Pi(k) ds_reads — consumed after softmax
      const int sw = (k>>1)&3;
      const float* pb = &sP[k<<4];
      const float4 Pi[4] = { ld4(pb + ((0^sw)<<2)), ld4(pb + ((1^sw)<<2)),
                             ld4(pb + ((2^sw)<<2)), ld4(pb + ((3^sw)<<2)) };
      // (4) softmax + moments on previous k's v — pure VALU, hides (1)+(3)
      softmax_moments(vA, fA);
      // (5) compute v(k) — waits land here
      compute_v(vA, Pi, w0, w1, w2, w3);
    }
    // epilogue: softmax+moments for the last k
    softmax_moments(vA, sA[(KT-1)*KSG + ks]);
    stats();
  }

  // ---- epilogue ----
  out[(size_t)n*544 + tid] = sMu[(tid>>4)*17 + (tid&15)];
  if (tid < CC) out[(size_t)n*544 + 512 + tid] = sAo[tid];
}

extern "C" void kernel_launch(void* const* d_in, const int* in_sizes, int n_in,
                              void* d_out, int out_size, void* d_ws, size_t ws_size,
                              hipStream_t stream) {
  (void)in_sizes; (void)n_in; (void)d_ws; (void)ws_size; (void)out_size;
  const float* x  = (const float*)d_in[0];
  const float* w  = (const float*)d_in[1];
  const float* ba = (const float*)d_in[2];
  const float* bu = (const float*)d_in[3];
  float* out = (float*)d_out;
  convcaps_em_kernel<<<dim3(392), dim3(NTH), 0, stream>>>(x, w, ba, bu, out);
}